// Round 4
// baseline (97.310 us; speedup 1.0000x reference)
//
#include <hip/hip_runtime.h>
#include <hip/hip_bf16.h>
#include <math.h>

#define N_NODES 512
#define S_STEPS 64
#define M_EV    32768
#define DELTA_F 1.5625f
#define EPS_F   1e-12f
#define TILE    16
#define NT      (N_NODES / TILE)        // 32
#define NBLK    (NT * (NT + 1) / 2)     // 528
#define SCHUNK  16
#define NCHUNK  4
#define GRID_PAIR (NBLK * NCHUNK)       // 2112
#define FIX_SCALE 1048576.0             // 2^20

// ws layout:
//   floats at base: [0..63] c0, [64..127] c1, [128..191] c2,
//                   [256..319] occ, [320..383] T = tf - ts
//   byte 2048: unsigned long long accD, accI;  byte 2064: uint ticket

__device__ __forceinline__ int bucket_key(float t) {
    float stepf = floorf(t / DELTA_F);
    float cl = fminf(fmaxf(stepf, 0.f), 63.f);
    return (int)cl;
}

__device__ __forceinline__ int lower_bound_key(const float* __restrict__ data, int target) {
    int lo = 0, len = M_EV;
    while (len > 0) {
        int half = len >> 1;
        int mid = lo + half;
        if (bucket_key(data[3 * mid + 2]) < target) { lo = mid + 1; len -= half + 1; }
        else { len = half; }
    }
    return lo;
}

// branchless erf, Abramowitz-Stegun 7.1.26 (|abs err| ~ 3e-7)
__device__ __forceinline__ float erf_fast(float x) {
    float ax = fabsf(x);
    float t  = __builtin_amdgcn_rcpf(fmaf(0.3275911f, ax, 1.0f));
    float y  = t * fmaf(t, fmaf(t, fmaf(t, fmaf(t, 1.061405429f, -1.453152027f),
                                          1.421413741f), -0.284496736f), 0.254829592f);
    float e  = __expf(-ax * ax);
    float r  = fmaf(-y, e, 1.0f);
    return __builtin_copysignf(r, x);
}

__global__ __launch_bounds__(256) void bucket_stats(const float* __restrict__ data,
                                                    float* __restrict__ ws_f,
                                                    unsigned long long* __restrict__ acc) {
    int s   = blockIdx.x;
    int tid = threadIdx.x;
    __shared__ int sLo, sHi;
    __shared__ int   wcnt[4];
    __shared__ float wsdd[4], wsdd2[4];

    if (blockIdx.x == 0 && tid == 128) {   // zero fused-reduction state (separate wave)
        acc[0] = 0ull; acc[1] = 0ull;
        ((unsigned int*)acc)[4] = 0u;      // ticket at byte offset 16
    }
    if (tid == 0)  sLo = lower_bound_key(data, s);
    if (tid == 64) sHi = lower_bound_key(data, s + 1);
    __syncthreads();
    int lo = sLo, hi = sHi;

    int   cnt = 0;
    float sdd = 0.f, sdd2 = 0.f;
    for (int m = lo + tid; m < hi; m += 256) {
        float t = data[3 * m + 2];
        float stepf = floorf(t / DELTA_F);
        float dd = t - stepf * DELTA_F;
        cnt++; sdd += dd; sdd2 += dd * dd;
    }
    for (int off = 32; off; off >>= 1) {
        cnt  += __shfl_down(cnt,  off);
        sdd  += __shfl_down(sdd,  off);
        sdd2 += __shfl_down(sdd2, off);
    }
    int wave = tid >> 6;
    if ((tid & 63) == 0) { wcnt[wave] = cnt; wsdd[wave] = sdd; wsdd2[wave] = sdd2; }
    __syncthreads();
    if (tid == 0) {
        int   c  = wcnt[0] + wcnt[1] + wcnt[2] + wcnt[3];
        float s1 = wsdd[0] + wsdd[1] + wsdd[2] + wsdd[3];
        float s2 = wsdd2[0] + wsdd2[1] + wsdd2[2] + wsdd2[3];
        ws_f[s]       = (float)c;
        ws_f[64 + s]  = s1;
        ws_f[128 + s] = s2;
        ws_f[256 + s] = (c > 0) ? 1.f : 0.f;
        float ts = data[3 * min(lo, M_EV - 1) + 2];
        float tf = data[3 * min(hi, M_EV - 1) + 2];
        ws_f[320 + s] = tf - ts;     // T
    }
}

__global__ __launch_bounds__(256) void pair_kernel(
        const float* __restrict__ z0, const float* __restrict__ v0,
        const float* __restrict__ beta, const float* __restrict__ ws_f,
        unsigned long long* __restrict__ acc, float* __restrict__ out) {
    __shared__ float4 Pi[SCHUNK][17];
    __shared__ float4 Pj[SCHUNK][17];
    __shared__ float sc0[SCHUNK], sc1[SCHUNK], sc2[SCHUNK], sT[SCHUNK], socc[SCHUNK];
    __shared__ double wD[4], wI[4];

    int bid   = blockIdx.x;
    int l     = bid >> 2;
    int chunk = bid & 3;
    int s0    = chunk * SCHUNK;

    int it = 0, rem = l;
    while (rem >= NT - it) { rem -= NT - it; ++it; }
    int jt = it + rem;

    int tid  = threadIdx.x;
    int wave = tid >> 6, lane = tid & 63;   // 256 threads = 4 waves of 64

    if (tid < SCHUNK) {
        int s = s0 + tid;
        sc0[tid]  = ws_f[s];
        sc1[tid]  = ws_f[64 + s];
        sc2[tid]  = ws_f[128 + s];
        socc[tid] = ws_f[256 + s];
        sT[tid]   = ws_f[320 + s];
    }

    // staging: 4 waves x 8 slab entries; wave-64 prefix scan over steps gives Z
    for (int e = wave * 8; e < wave * 8 + 8; ++e) {
        int loc = e & 15;
        int n = (e < 16 ? it : jt) * TILE + loc;
        float vx = v0[n * 128 + lane];
        float vy = v0[n * 128 + 64 + lane];
        float ix = vx, iy = vy;
        #pragma unroll
        for (int off = 1; off < 64; off <<= 1) {
            float ux = __shfl_up(ix, off);
            float uy = __shfl_up(iy, off);
            if (lane >= off) { ix += ux; iy += uy; }
        }
        float zx = fmaf(DELTA_F, ix - vx, z0[2 * n]);      // exclusive prefix
        float zy = fmaf(DELTA_F, iy - vy, z0[2 * n + 1]);
        int srel = lane - s0;
        if (srel >= 0 && srel < SCHUNK) {
            float4 val = make_float4(zx, zy, vx, vy);
            if (e < 16) Pi[srel][loc] = val; else Pj[srel][loc] = val;
        }
    }
    __syncthreads();

    int li = tid >> 4, lj = tid & 15;
    int i = it * TILE + li, j = jt * TILE + lj;
    float accD = 0.f, accI = 0.f;
    float b = beta[0];

    if (i < j) {
        #pragma unroll
        for (int s = 0; s < SCHUNK; ++s) {
            float4 a = Pi[s][li];
            float4 c = Pj[s][lj];
            float dx  = a.x - c.x,  dy  = a.y - c.y;
            float dvx = a.z - c.z,  dvy = a.w - c.w;
            float q  = dx * dx + dy * dy;
            float p  = fmaf(dx, dvx, dy * dvy);
            float vv = fmaf(dvx, dvx, dvy * dvy);
            accD += fmaf(sc0[s], q, fmaf(2.f * sc1[s], p, sc2[s] * vv));
            float rr    = vv + EPS_F;
            float inv_r = __builtin_amdgcn_rsqf(rr);
            float r     = rr * inv_r;
            float por   = p * inv_r;
            float ex    = __expf(fmaf(por, por, b - q));
            float integ = ex * (0.8862269254527580f * inv_r)
                          * (erf_fast(fmaf(r, sT[s], por)) - erf_fast(por));
            accI = fmaf(socc[s], integ, accI);
        }
    }

    // wave reduce (deterministic), then 4 wave partials -> i64 atomics
    for (int off = 32; off; off >>= 1) {
        accD += __shfl_down(accD, off);
        accI += __shfl_down(accI, off);
    }
    if (lane == 0) { wD[wave] = (double)accD; wI[wave] = (double)accI; }
    __syncthreads();
    if (tid == 0) {
        double D = wD[0] + wD[1] + wD[2] + wD[3];
        double I = wI[0] + wI[1] + wI[2] + wI[3];
        atomicAdd(&acc[0], (unsigned long long)(long long)llrint(D * FIX_SCALE));
        atomicAdd(&acc[1], (unsigned long long)(long long)llrint(I * FIX_SCALE));
        __threadfence();
        unsigned int old = atomicAdd(&((unsigned int*)acc)[4], 1u);
        if (old == (unsigned int)(GRID_PAIR - 1)) {
            __threadfence();
            unsigned long long Du = atomicAdd(&acc[0], 0ull);
            unsigned long long Iu = atomicAdd(&acc[1], 0ull);
            double Dd = (double)(long long)Du / FIX_SCALE;
            double Id = (double)(long long)Iu / FIX_SCALE;
            double npairs = (double)N_NODES * (double)(N_NODES - 1) * 0.5;
            out[0] = (float)((double)b * (double)M_EV * npairs - Dd - Id);
        }
    }
}

extern "C" void kernel_launch(void* const* d_in, const int* in_sizes, int n_in,
                              void* d_out, int out_size, void* d_ws, size_t ws_size,
                              hipStream_t stream) {
    const float* data = (const float*)d_in[0];
    const float* z0   = (const float*)d_in[3];
    const float* v0   = (const float*)d_in[4];
    const float* beta = (const float*)d_in[5];

    float* ws_f = (float*)d_ws;
    unsigned long long* acc = (unsigned long long*)((char*)d_ws + 2048);
    float* out = (float*)d_out;

    bucket_stats<<<64, 256, 0, stream>>>(data, ws_f, acc);
    pair_kernel<<<GRID_PAIR, 256, 0, stream>>>(z0, v0, beta, ws_f, acc, out);
}

// Round 5
// 32.551 us; speedup vs baseline: 2.9895x; 2.9895x over previous
//
#include <hip/hip_runtime.h>
#include <hip/hip_bf16.h>
#include <math.h>

#define N_NODES 512
#define S_STEPS 64
#define M_EV    32768
#define DELTA_F 1.5625f
#define EPS_F   1e-12f
#define TILE    16
#define NT      (N_NODES / TILE)        // 32
#define NBLK    (NT * (NT + 1) / 2)     // 528
#define SCHUNK  16

// ws layout (floats at base):
//   [0..63] c0, [64..127] c1, [128..191] c2, [256..319] occ, [320..383] T
//   byte 2048: double partials[NBLK*2]  (8448 B)

__device__ __forceinline__ int bucket_key(float t) {
    float stepf = floorf(t / DELTA_F);
    float cl = fminf(fmaxf(stepf, 0.f), 63.f);
    return (int)cl;
}

__device__ __forceinline__ int lower_bound_key(const float* __restrict__ data, int target) {
    int lo = 0, len = M_EV;
    while (len > 0) {
        int half = len >> 1;
        int mid = lo + half;
        if (bucket_key(data[3 * mid + 2]) < target) { lo = mid + 1; len -= half + 1; }
        else { len = half; }
    }
    return lo;
}

// branchless erf, Abramowitz-Stegun 7.1.26 (|abs err| ~ 3e-7)
__device__ __forceinline__ float erf_fast(float x) {
    float ax = fabsf(x);
    float t  = __builtin_amdgcn_rcpf(fmaf(0.3275911f, ax, 1.0f));
    float y  = t * fmaf(t, fmaf(t, fmaf(t, fmaf(t, 1.061405429f, -1.453152027f),
                                          1.421413741f), -0.284496736f), 0.254829592f);
    float e  = __expf(-ax * ax);
    float r  = fmaf(-y, e, 1.0f);
    return __builtin_copysignf(r, x);
}

__global__ __launch_bounds__(256) void bucket_stats(const float* __restrict__ data,
                                                    float* __restrict__ ws_f) {
    int s   = blockIdx.x;
    int tid = threadIdx.x;
    __shared__ int sLo, sHi;
    __shared__ int   wcnt[4];
    __shared__ float wsdd[4], wsdd2[4];

    if (tid == 0)  sLo = lower_bound_key(data, s);
    if (tid == 64) sHi = lower_bound_key(data, s + 1);
    __syncthreads();
    int lo = sLo, hi = sHi;

    int   cnt = 0;
    float sdd = 0.f, sdd2 = 0.f;
    for (int m = lo + tid; m < hi; m += 256) {
        float t = data[3 * m + 2];
        float stepf = floorf(t / DELTA_F);
        float dd = t - stepf * DELTA_F;
        cnt++; sdd += dd; sdd2 += dd * dd;
    }
    for (int off = 32; off; off >>= 1) {
        cnt  += __shfl_down(cnt,  off);
        sdd  += __shfl_down(sdd,  off);
        sdd2 += __shfl_down(sdd2, off);
    }
    int wave = tid >> 6;
    if ((tid & 63) == 0) { wcnt[wave] = cnt; wsdd[wave] = sdd; wsdd2[wave] = sdd2; }
    __syncthreads();
    if (tid == 0) {
        int   c  = wcnt[0] + wcnt[1] + wcnt[2] + wcnt[3];
        float s1 = wsdd[0] + wsdd[1] + wsdd[2] + wsdd[3];
        float s2 = wsdd2[0] + wsdd2[1] + wsdd2[2] + wsdd2[3];
        ws_f[s]       = (float)c;
        ws_f[64 + s]  = s1;
        ws_f[128 + s] = s2;
        ws_f[256 + s] = (c > 0) ? 1.f : 0.f;
        float ts = data[3 * min(lo, M_EV - 1) + 2];
        float tf = data[3 * min(hi, M_EV - 1) + 2];
        ws_f[320 + s] = tf - ts;     // T = tf - ts (closed form via sortedness)
    }
}

__global__ __launch_bounds__(1024, 8) void pair_kernel(
        const float* __restrict__ z0, const float* __restrict__ v0,
        const float* __restrict__ beta, const float* __restrict__ ws_f,
        double* __restrict__ partials) {
    __shared__ float4 Pi[S_STEPS][17];
    __shared__ float4 Pj[S_STEPS][17];
    __shared__ float sc0[64], sc1[64], sc2[64], sT[64], socc[64];
    __shared__ double wD[16], wI[16];

    int l = blockIdx.x;
    int it = 0, rem = l;
    while (rem >= NT - it) { rem -= NT - it; ++it; }
    int jt = it + rem;

    int tid  = threadIdx.x;
    int wave = tid >> 6, lane = tid & 63;   // 16 waves of 64

    if (tid < 64) {
        sc0[tid]  = ws_f[tid];
        sc1[tid]  = ws_f[64 + tid];
        sc2[tid]  = ws_f[128 + tid];
        socc[tid] = ws_f[256 + tid];
        sT[tid]   = ws_f[320 + tid];
    }

    // staging: 16 waves x 2 slab entries; lane == step s; wave-64 prefix scan gives Z
    for (int e = wave * 2; e < wave * 2 + 2; ++e) {
        int loc = e & 15;
        int n = (e < 16 ? it : jt) * TILE + loc;
        float vx = v0[n * 128 + lane];
        float vy = v0[n * 128 + 64 + lane];
        float ix = vx, iy = vy;
        #pragma unroll
        for (int off = 1; off < 64; off <<= 1) {
            float ux = __shfl_up(ix, off);
            float uy = __shfl_up(iy, off);
            if (lane >= off) { ix += ux; iy += uy; }
        }
        float zx = fmaf(DELTA_F, ix - vx, z0[2 * n]);      // exclusive prefix
        float zy = fmaf(DELTA_F, iy - vy, z0[2 * n + 1]);
        float4 val = make_float4(zx, zy, vx, vy);
        if (e < 16) Pi[lane][loc] = val; else Pj[lane][loc] = val;
    }
    __syncthreads();

    // compute: 4 chunks x 256 threads; each thread = one (i,j) pair, 16 steps
    int chunk = tid >> 8;
    int r  = tid & 255;
    int li = r >> 4, lj = r & 15;
    int i = it * TILE + li, j = jt * TILE + lj;
    float accD = 0.f, accI = 0.f;
    float b = beta[0];

    if (i < j) {
        int s0 = chunk * SCHUNK;
        #pragma unroll
        for (int ss = 0; ss < SCHUNK; ++ss) {
            int s = s0 + ss;
            float4 a = Pi[s][li];
            float4 c = Pj[s][lj];
            float dx  = a.x - c.x,  dy  = a.y - c.y;
            float dvx = a.z - c.z,  dvy = a.w - c.w;
            float q  = dx * dx + dy * dy;
            float p  = fmaf(dx, dvx, dy * dvy);
            float vv = fmaf(dvx, dvx, dvy * dvy);
            accD += fmaf(sc0[s], q, fmaf(2.f * sc1[s], p, sc2[s] * vv));
            float rr    = vv + EPS_F;
            float inv_r = __builtin_amdgcn_rsqf(rr);
            float rt    = rr * inv_r;
            float por   = p * inv_r;
            float ex    = __expf(fmaf(por, por, b - q));
            float integ = ex * (0.8862269254527580f * inv_r)
                          * (erf_fast(fmaf(rt, sT[s], por)) - erf_fast(por));
            accI = fmaf(socc[s], integ, accI);
        }
    }

    // deterministic reduce: wave tree -> 16 wave partials -> tid 0 sums -> plain store
    for (int off = 32; off; off >>= 1) {
        accD += __shfl_down(accD, off);
        accI += __shfl_down(accI, off);
    }
    if (lane == 0) { wD[wave] = (double)accD; wI[wave] = (double)accI; }
    __syncthreads();
    if (tid == 0) {
        double D = 0.0, I = 0.0;
        #pragma unroll
        for (int k = 0; k < 16; ++k) { D += wD[k]; I += wI[k]; }
        partials[2 * l]     = D;
        partials[2 * l + 1] = I;
    }
}

__global__ void final_reduce(const float* __restrict__ beta,
                             const double* __restrict__ partials,
                             float* __restrict__ out) {
    __shared__ double sD[256], sI[256];
    int tid = threadIdx.x;
    double dD = 0.0, dI = 0.0;
    for (int l = tid; l < NBLK; l += 256) {
        dD += partials[2 * l];
        dI += partials[2 * l + 1];
    }
    sD[tid] = dD; sI[tid] = dI;
    __syncthreads();
    for (int off = 128; off; off >>= 1) {
        if (tid < off) { sD[tid] += sD[tid + off]; sI[tid] += sI[tid + off]; }
        __syncthreads();
    }
    if (tid == 0) {
        double npairs = (double)N_NODES * (double)(N_NODES - 1) * 0.5;
        double ev = (double)beta[0] * (double)M_EV * npairs - sD[0];
        out[0] = (float)(ev - sI[0]);
    }
}

extern "C" void kernel_launch(void* const* d_in, const int* in_sizes, int n_in,
                              void* d_out, int out_size, void* d_ws, size_t ws_size,
                              hipStream_t stream) {
    const float* data = (const float*)d_in[0];
    const float* z0   = (const float*)d_in[3];
    const float* v0   = (const float*)d_in[4];
    const float* beta = (const float*)d_in[5];

    float*  ws_f     = (float*)d_ws;
    double* partials = (double*)((char*)d_ws + 2048);
    float*  out      = (float*)d_out;

    bucket_stats<<<64, 256, 0, stream>>>(data, ws_f);
    pair_kernel<<<NBLK, 1024, 0, stream>>>(z0, v0, beta, ws_f, partials);
    final_reduce<<<1, 256, 0, stream>>>(beta, partials, out);
}

// Round 6
// 27.585 us; speedup vs baseline: 3.5276x; 1.1800x over previous
//
#include <hip/hip_runtime.h>
#include <hip/hip_bf16.h>
#include <math.h>

#define N_NODES 512
#define S_STEPS 64
#define M_EV    32768
#define DELTA_F 1.5625f
#define EPS_F   1e-12f
#define TILE    16
#define NT      (N_NODES / TILE)        // 32
#define NOFF    (NT * (NT - 1) / 2)     // 496 strict-upper tiles
#define NBLK    (NOFF + NT / 2)         // 512 blocks total
#define SCHUNK  16

// ws layout:
//   byte 0:    float4 sC[64]  (c0, 2*c1, c2, T_eff)            1 KB
//   byte 2048: double partials[NBLK*2]                         8 KB

__device__ __forceinline__ int bucket_key(float t) {
    float stepf = floorf(t / DELTA_F);
    float cl = fminf(fmaxf(stepf, 0.f), 63.f);
    return (int)cl;
}

__device__ __forceinline__ int lower_bound_key(const float* __restrict__ data, int target) {
    int lo = 0, len = M_EV;
    while (len > 0) {
        int half = len >> 1;
        int mid = lo + half;
        if (bucket_key(data[3 * mid + 2]) < target) { lo = mid + 1; len -= half + 1; }
        else { len = half; }
    }
    return lo;
}

// branchless erf, Abramowitz-Stegun 7.1.26 (|abs err| ~ 3e-7)
__device__ __forceinline__ float erf_fast(float x) {
    float ax = fabsf(x);
    float t  = __builtin_amdgcn_rcpf(fmaf(0.3275911f, ax, 1.0f));
    float y  = t * fmaf(t, fmaf(t, fmaf(t, fmaf(t, 1.061405429f, -1.453152027f),
                                          1.421413741f), -0.284496736f), 0.254829592f);
    float e  = __expf(-ax * ax);
    float r  = fmaf(-y, e, 1.0f);
    return __builtin_copysignf(r, x);
}

__global__ __launch_bounds__(256) void bucket_stats(const float* __restrict__ data,
                                                    float4* __restrict__ ws_c4) {
    int s   = blockIdx.x;
    int tid = threadIdx.x;
    __shared__ int sLo, sHi;
    __shared__ int   wcnt[4];
    __shared__ float wsdd[4], wsdd2[4];

    if (tid == 0)  sLo = lower_bound_key(data, s);
    if (tid == 64) sHi = lower_bound_key(data, s + 1);
    __syncthreads();
    int lo = sLo, hi = sHi;

    int   cnt = 0;
    float sdd = 0.f, sdd2 = 0.f;
    for (int m = lo + tid; m < hi; m += 256) {
        float t = data[3 * m + 2];
        float stepf = floorf(t / DELTA_F);
        float dd = t - stepf * DELTA_F;
        cnt++; sdd += dd; sdd2 += dd * dd;
    }
    for (int off = 32; off; off >>= 1) {
        cnt  += __shfl_down(cnt,  off);
        sdd  += __shfl_down(sdd,  off);
        sdd2 += __shfl_down(sdd2, off);
    }
    int wave = tid >> 6;
    if ((tid & 63) == 0) { wcnt[wave] = cnt; wsdd[wave] = sdd; wsdd2[wave] = sdd2; }
    __syncthreads();
    if (tid == 0) {
        int   c  = wcnt[0] + wcnt[1] + wcnt[2] + wcnt[3];
        float s1 = wsdd[0] + wsdd[1] + wsdd[2] + wsdd[3];
        float s2 = wsdd2[0] + wsdd2[1] + wsdd2[2] + wsdd2[3];
        // T = tf - ts via sortedness: hi is first event of next occupied bucket
        float ts = data[3 * min(lo, M_EV - 1) + 2];
        float tf = data[3 * min(hi, M_EV - 1) + 2];
        float Teff = (c > 0) ? (tf - ts) : 0.f;   // T=0 => erf diff == 0 exactly
        ws_c4[s] = make_float4((float)c, 2.f * s1, s2, Teff);
    }
}

__global__ __launch_bounds__(1024, 8) void pair_kernel(
        const float* __restrict__ z0, const float* __restrict__ v0,
        const float* __restrict__ beta, const float4* __restrict__ ws_c4,
        double* __restrict__ partials) {
    __shared__ float4 Pi[S_STEPS][17];
    __shared__ float4 Pj[S_STEPS][17];
    __shared__ float4 sC[64];
    __shared__ double wD[16], wI[16];

    int l = blockIdx.x;
    bool isDiag = (l >= NOFF);
    int it, jt;
    if (!isDiag) {                 // strict upper-tri tile enumeration
        int it_ = 0, rem = l;
        while (rem >= NT - 1 - it_) { rem -= NT - 1 - it_; ++it_; }
        it = it_; jt = it_ + 1 + rem;
    } else {                       // two diagonal tiles per block
        int k = l - NOFF;
        it = 2 * k; jt = 2 * k + 1;
    }

    int tid  = threadIdx.x;
    int wave = tid >> 6, lane = tid & 63;   // 16 waves of 64

    if (tid < 64) sC[tid] = ws_c4[tid];

    // staging: 16 waves x 2 slab entries; lane == step s; wave-64 prefix scan gives Z
    for (int e = wave * 2; e < wave * 2 + 2; ++e) {
        int loc = e & 15;
        int n = (e < 16 ? it : jt) * TILE + loc;
        float vx = v0[n * 128 + lane];
        float vy = v0[n * 128 + 64 + lane];
        float ix = vx, iy = vy;
        #pragma unroll
        for (int off = 1; off < 64; off <<= 1) {
            float ux = __shfl_up(ix, off);
            float uy = __shfl_up(iy, off);
            if (lane >= off) { ix += ux; iy += uy; }
        }
        float zx = fmaf(DELTA_F, ix - vx, z0[2 * n]);      // exclusive prefix
        float zy = fmaf(DELTA_F, iy - vy, z0[2 * n + 1]);
        float4 val = make_float4(zx, zy, vx, vy);
        if (e < 16) Pi[lane][loc] = val; else Pj[lane][loc] = val;
    }
    __syncthreads();

    // compute: 4 chunks x 256 threads; each active thread = one (i,j) pair, 16 steps
    int chunk = tid >> 8;
    int r  = tid & 255;
    int li = r >> 4, lj = r & 15;

    const float4* rowA;
    const float4* rowB;
    bool act;
    if (!isDiag) {                       // i = it*16+li < j = jt*16+lj always
        rowA = &Pi[0][li]; rowB = &Pj[0][lj]; act = true;
    } else if (li < lj) {                // tile it: pair (li, lj)
        rowA = &Pi[0][li]; rowB = &Pi[0][lj]; act = true;
    } else {                             // tile jt: pair (lj, li+1); li==15 idle
        int bb = min(li + 1, 15);
        rowA = &Pj[0][lj]; rowB = &Pj[0][bb]; act = (li < 15);
    }

    float accD = 0.f, accI = 0.f;
    float b = beta[0];

    if (act) {
        int s0 = chunk * SCHUNK;
        const float4* pA = rowA + s0 * 17;
        const float4* pB = rowB + s0 * 17;
        #pragma unroll 4
        for (int ss = 0; ss < SCHUNK; ++ss) {
            float4 a = pA[ss * 17];
            float4 c = pB[ss * 17];
            float4 k = sC[s0 + ss];
            float dx  = a.x - c.x,  dy  = a.y - c.y;
            float dvx = a.z - c.z,  dvy = a.w - c.w;
            float q  = dx * dx + dy * dy;
            float p  = fmaf(dx, dvx, dy * dvy);
            float vv = fmaf(dvx, dvx, dvy * dvy);
            accD += fmaf(k.x, q, fmaf(k.y, p, k.z * vv));
            float rr    = vv + EPS_F;
            float inv_r = __builtin_amdgcn_rsqf(rr);
            float rt    = rr * inv_r;
            float por   = p * inv_r;
            float ex    = __expf(fmaf(por, por, b - q));   // por^2 <= q -> ex <= e^b
            float integ = ex * (0.8862269254527580f * inv_r)
                          * (erf_fast(fmaf(rt, k.w, por)) - erf_fast(por));
            accI += integ;                                  // T_eff==0 -> integ==0
        }
    }

    // deterministic reduce: wave tree -> 16 wave partials -> tid 0 sums -> plain store
    for (int off = 32; off; off >>= 1) {
        accD += __shfl_down(accD, off);
        accI += __shfl_down(accI, off);
    }
    if (lane == 0) { wD[wave] = (double)accD; wI[wave] = (double)accI; }
    __syncthreads();
    if (tid == 0) {
        double D = 0.0, I = 0.0;
        #pragma unroll
        for (int k = 0; k < 16; ++k) { D += wD[k]; I += wI[k]; }
        partials[2 * l]     = D;
        partials[2 * l + 1] = I;
    }
}

__global__ void final_reduce(const float* __restrict__ beta,
                             const double* __restrict__ partials,
                             float* __restrict__ out) {
    __shared__ double sD[256], sI[256];
    int tid = threadIdx.x;
    double dD = 0.0, dI = 0.0;
    for (int l = tid; l < NBLK; l += 256) {
        dD += partials[2 * l];
        dI += partials[2 * l + 1];
    }
    sD[tid] = dD; sI[tid] = dI;
    __syncthreads();
    for (int off = 128; off; off >>= 1) {
        if (tid < off) { sD[tid] += sD[tid + off]; sI[tid] += sI[tid + off]; }
        __syncthreads();
    }
    if (tid == 0) {
        double npairs = (double)N_NODES * (double)(N_NODES - 1) * 0.5;
        double ev = (double)beta[0] * (double)M_EV * npairs - sD[0];
        out[0] = (float)(ev - sI[0]);
    }
}

extern "C" void kernel_launch(void* const* d_in, const int* in_sizes, int n_in,
                              void* d_out, int out_size, void* d_ws, size_t ws_size,
                              hipStream_t stream) {
    const float* data = (const float*)d_in[0];
    const float* z0   = (const float*)d_in[3];
    const float* v0   = (const float*)d_in[4];
    const float* beta = (const float*)d_in[5];

    float4* ws_c4    = (float4*)d_ws;
    double* partials = (double*)((char*)d_ws + 2048);
    float*  out      = (float*)d_out;

    bucket_stats<<<64, 256, 0, stream>>>(data, ws_c4);
    pair_kernel<<<NBLK, 1024, 0, stream>>>(z0, v0, beta, ws_c4, partials);
    final_reduce<<<1, 256, 0, stream>>>(beta, partials, out);
}